// Round 5
// baseline (354.691 us; speedup 1.0000x reference)
//
#include <hip/hip_runtime.h>
#include <math.h>

#define BB 8
#define HH 56
#define WWD 56
#define NN 3136
#define CC 256
#define DIMM 512
#define NHEAD 8
#define NQ 64
#define EPSF 1e-5f
#define SCALEF 0.04419417382415922f

typedef __attribute__((ext_vector_type(8))) short short8;
typedef __attribute__((ext_vector_type(4))) float floatx4;

__device__ __forceinline__ float gelu_f(float x) {
    return 0.5f * x * (1.f + erff(x * 0.70710678118654752f));
}
__device__ __forceinline__ unsigned short f2bf(float f) {
    union { float f; unsigned u; } v; v.f = f;
    return (unsigned short)((v.u + 0x7fffu + ((v.u >> 16) & 1u)) >> 16);
}
__device__ __forceinline__ float bf2f(unsigned short u) {
    union { unsigned u; float f; } v; v.u = ((unsigned)u) << 16;
    return v.f;
}
__device__ __forceinline__ float bfl(unsigned p) {
    union { unsigned u; float f; } v; v.u = p << 16; return v.f;
}
__device__ __forceinline__ float bfh(unsigned p) {
    union { unsigned u; float f; } v; v.u = p & 0xffff0000u; return v.f;
}

__global__ __launch_bounds__(256) void cast_k(const float* __restrict__ s,
                                              unsigned short* __restrict__ d, int n) {
    int i = blockIdx.x * 256 + threadIdx.x;
    if (i < n) d[i] = f2bf(s[i]);
}

// ===========================================================================
// MFMA GEMM: v16[m, c] = bf16( sum_{k<256} x[m*512+k] * w16[c*256+k] )
// Output (B,N,C) bf16 via LDS-transpose epilogue -> fully coalesced stores.
// ===========================================================================
__global__ __launch_bounds__(256) void gemm_v_mfma(
    const float* __restrict__ x, const unsigned short* __restrict__ w16,
    unsigned short* __restrict__ v16) {
    __shared__ short As[128 * 72];
    __shared__ short Bs[64 * 72];
    int m0 = blockIdx.x * 128, c0 = blockIdx.y * 64;
    int tid = threadIdx.x;
    int lane = tid & 63, wv = tid >> 6;
    int quad = lane >> 4, l16 = lane & 15;
    floatx4 zero = {0.f, 0.f, 0.f, 0.f};
    floatx4 acc[2][4];
#pragma unroll
    for (int mi = 0; mi < 2; mi++)
#pragma unroll
        for (int ci = 0; ci < 4; ci++) acc[mi][ci] = zero;

    for (int k0 = 0; k0 < 256; k0 += 64) {
        {
            int m = tid >> 1;
            int ob = (tid & 1) * 4;
            const float* src = x + (size_t)(m0 + m) * DIMM + k0 + ob * 8;
            short* dst = &As[m * 72 + ob * 8];
#pragma unroll
            for (int i2 = 0; i2 < 4; i2++) {
                floatx4 f0 = *(const floatx4*)(src + i2 * 8);
                floatx4 f1 = *(const floatx4*)(src + i2 * 8 + 4);
                short8 pk;
                pk[0] = (short)f2bf(f0[0]); pk[1] = (short)f2bf(f0[1]);
                pk[2] = (short)f2bf(f0[2]); pk[3] = (short)f2bf(f0[3]);
                pk[4] = (short)f2bf(f1[0]); pk[5] = (short)f2bf(f1[1]);
                pk[6] = (short)f2bf(f1[2]); pk[7] = (short)f2bf(f1[3]);
                *(short8*)(dst + i2 * 8) = pk;
            }
        }
#pragma unroll
        for (int i2 = 0; i2 < 2; i2++) {
            int idx = tid + 256 * i2;
            int c = idx >> 3, o = idx & 7;
            *(short8*)&Bs[c * 72 + o * 8] =
                *(const short8*)(const short*)(w16 + (size_t)(c0 + c) * 256 + k0 + o * 8);
        }
        __syncthreads();
#pragma unroll
        for (int kc = 0; kc < 2; kc++) {
            short8 af[2], bf[4];
#pragma unroll
            for (int mi = 0; mi < 2; mi++)
                af[mi] = *(const short8*)&As[(wv * 32 + mi * 16 + l16) * 72 + (kc * 4 + quad) * 8];
#pragma unroll
            for (int ci = 0; ci < 4; ci++)
                bf[ci] = *(const short8*)&Bs[(ci * 16 + l16) * 72 + (kc * 4 + quad) * 8];
#pragma unroll
            for (int mi = 0; mi < 2; mi++)
#pragma unroll
                for (int ci = 0; ci < 4; ci++)
                    acc[mi][ci] = __builtin_amdgcn_mfma_f32_16x16x32_bf16(
                        af[mi], bf[ci], acc[mi][ci], 0, 0, 0);
        }
        __syncthreads();
    }
    // transpose epilogue: acc -> LDS [m][c] -> coalesced 16B global stores
#pragma unroll
    for (int mi = 0; mi < 2; mi++)
#pragma unroll
        for (int ci = 0; ci < 4; ci++)
#pragma unroll
            for (int r = 0; r < 4; r++)
                As[(wv * 32 + mi * 16 + quad * 4 + r) * 72 + ci * 16 + l16] =
                    (short)f2bf(acc[mi][ci][r]);
    __syncthreads();
    {
        int m = tid >> 1, half = tid & 1;
        unsigned short* dst = v16 + (size_t)(m0 + m) * CC + c0 + half * 32;
        const short* srcl = &As[m * 72 + half * 32];
#pragma unroll
        for (int u = 0; u < 4; u++)
            *(short8*)((short*)dst + u * 8) = *(const short8*)(srcl + u * 8);
    }
}

// ===========================================================================
// NHWC depthwise 3x3 + BN. 2 channels/thread, 2 n-positions/block.
// DUAL: also writes gelu(bn) to out2 (conv1 path).
// ===========================================================================
template <bool DUAL>
__global__ __launch_bounds__(256) void dwconv_nhwc_k(
    const unsigned short* __restrict__ in16, const float* __restrict__ w,
    const float* __restrict__ g, const float* __restrict__ bp,
    const float* __restrict__ mo, const float* __restrict__ vo,
    unsigned short* __restrict__ out16, unsigned short* __restrict__ out2) {
    int blk = blockIdx.x;                 // b * (NN/2) + npair
    int b = blk / (NN / 2), npair = blk % (NN / 2);
    int tid = threadIdx.x;
    int nl = tid >> 7;                    // wave-uniform
    int c = (tid & 127) * 2;
    int n = npair * 2 + nl;
    int y = n / WWD, x = n - y * WWD;
    const unsigned short* base = in16 + (size_t)b * NN * CC + c;
    float wA[9], wB[9];
#pragma unroll
    for (int t = 0; t < 9; t++) { wA[t] = w[c * 9 + t]; wB[t] = w[(c + 1) * 9 + t]; }
    float sA = g[c] * rsqrtf(vo[c] + EPSF);
    float shA = bp[c] - mo[c] * sA;
    float sB = g[c + 1] * rsqrtf(vo[c + 1] + EPSF);
    float shB = bp[c + 1] - mo[c + 1] * sB;
    float aA = 0.f, aB = 0.f;
#pragma unroll
    for (int dy = -1; dy <= 1; dy++) {
        int iy = y + dy;
        if (iy < 0 || iy >= HH) continue;
#pragma unroll
        for (int dx = -1; dx <= 1; dx++) {
            int ix = x + dx;
            if (ix < 0 || ix >= WWD) continue;
            unsigned pv = *(const unsigned*)(base + (size_t)(iy * WWD + ix) * CC);
            aA += bfl(pv) * wA[(dy + 1) * 3 + dx + 1];
            aB += bfh(pv) * wB[(dy + 1) * 3 + dx + 1];
        }
    }
    float rA = aA * sA + shA, rB = aB * sB + shB;
    size_t oidx = (size_t)(b * NN + n) * CC + c;
    *(unsigned*)(out16 + oidx) = (unsigned)f2bf(rA) | ((unsigned)f2bf(rB) << 16);
    if (DUAL)
        *(unsigned*)(out2 + oidx) =
            (unsigned)f2bf(gelu_f(rA)) | ((unsigned)f2bf(gelu_f(rB)) << 16);
}

// 7x7 avg+max pool over NHWC bf16 -> (B,C,64) fp32
__global__ __launch_bounds__(256) void pool_nhwc_k(
    const unsigned short* __restrict__ in16, float* __restrict__ oavg,
    float* __restrict__ omax) {
    int blk = blockIdx.x;  // b*64 + q
    int q = blk & 63, b = blk >> 6;
    int qy = q >> 3, qx = q & 7;
    int c = threadIdx.x;
    const unsigned short* base = in16 + (size_t)b * NN * CC + c;
    float sm = 0.f, mx = -INFINITY;
#pragma unroll
    for (int py = 0; py < 7; py++)
#pragma unroll
        for (int px = 0; px < 7; px++) {
            float t = bf2f(base[(size_t)((qy * 7 + py) * WWD + qx * 7 + px) * CC]);
            sm += t;
            mx = fmaxf(mx, t);
        }
    oavg[((size_t)b * CC + c) * 64 + q] = sm * (1.f / 49.f);
    omax[((size_t)b * CC + c) * 64 + q] = mx;
}

// ===========================================================================
// conv3 as MFMA GEMM, NHWC in/out: xh16[m, co] = bf16(gelu(bn3(W@X + bias)))
// A-staging: pure 16B copies from (B,N,C) bf16. LDS-transpose store epilogue.
// ===========================================================================
__global__ __launch_bounds__(256) void conv3_mfma(
    const unsigned short* __restrict__ xin, const unsigned short* __restrict__ w16,
    const float* __restrict__ bias, const float* __restrict__ g,
    const float* __restrict__ bparm, const float* __restrict__ mm,
    const float* __restrict__ vvv, unsigned short* __restrict__ out16) {
    __shared__ short As[128 * 72];
    __shared__ short Bs[64 * 72];
    int m0 = blockIdx.x * 128, c0 = blockIdx.y * 64;
    int tid = threadIdx.x;
    int lane = tid & 63, wv = tid >> 6;
    int quad = lane >> 4, l16 = lane & 15;
    floatx4 zero = {0.f, 0.f, 0.f, 0.f};
    floatx4 acc[2][4];
#pragma unroll
    for (int mi = 0; mi < 2; mi++)
#pragma unroll
        for (int ci = 0; ci < 4; ci++) acc[mi][ci] = zero;

    for (int k0 = 0; k0 < 256; k0 += 64) {
#pragma unroll
        for (int i2 = 0; i2 < 4; i2++) {
            int idx = tid + 256 * i2;
            int m = idx >> 3, o = idx & 7;
            *(short8*)&As[m * 72 + o * 8] =
                *(const short8*)(const short*)(xin + (size_t)(m0 + m) * CC + k0 + o * 8);
        }
#pragma unroll
        for (int i2 = 0; i2 < 2; i2++) {
            int idx = tid + 256 * i2;
            int c = idx >> 3, o = idx & 7;
            *(short8*)&Bs[c * 72 + o * 8] =
                *(const short8*)(const short*)(w16 + (size_t)(c0 + c) * CC + k0 + o * 8);
        }
        __syncthreads();
#pragma unroll
        for (int kc = 0; kc < 2; kc++) {
            short8 af[2], bf[4];
#pragma unroll
            for (int mi = 0; mi < 2; mi++)
                af[mi] = *(const short8*)&As[(wv * 32 + mi * 16 + l16) * 72 + (kc * 4 + quad) * 8];
#pragma unroll
            for (int ci = 0; ci < 4; ci++)
                bf[ci] = *(const short8*)&Bs[(ci * 16 + l16) * 72 + (kc * 4 + quad) * 8];
#pragma unroll
            for (int mi = 0; mi < 2; mi++)
#pragma unroll
                for (int ci = 0; ci < 4; ci++)
                    acc[mi][ci] = __builtin_amdgcn_mfma_f32_16x16x32_bf16(
                        af[mi], bf[ci], acc[mi][ci], 0, 0, 0);
        }
        __syncthreads();
    }
#pragma unroll
    for (int ci = 0; ci < 4; ci++) {
        int co = c0 + ci * 16 + l16;
        float s = g[co] * rsqrtf(vvv[co] + EPSF);
        float sh = bparm[co] - mm[co] * s;
        float bi = bias[co];
#pragma unroll
        for (int mi = 0; mi < 2; mi++)
#pragma unroll
            for (int r = 0; r < 4; r++)
                As[(wv * 32 + mi * 16 + quad * 4 + r) * 72 + ci * 16 + l16] =
                    (short)f2bf(gelu_f((acc[mi][ci][r] + bi) * s + sh));
    }
    __syncthreads();
    {
        int m = tid >> 1, half = tid & 1;
        unsigned short* dst = out16 + (size_t)(m0 + m) * CC + c0 + half * 32;
        const short* srcl = &As[m * 72 + half * 32];
#pragma unroll
        for (int u = 0; u < 4; u++)
            *(short8*)((short*)dst + u * 8) = *(const short8*)(srcl + u * 8);
    }
}

// ---------------------------------------------------------------------------
// attn_small[b,h,i,j] (fp32, 64x64 per (b,h))
// ---------------------------------------------------------------------------
__global__ __launch_bounds__(256) void attn_qk_k(
    const float* __restrict__ q1, const float* __restrict__ q2,
    const float* __restrict__ k1, const float* __restrict__ k2,
    float* __restrict__ attn_s) {
    int b = blockIdx.x >> 3, h = blockIdx.x & 7;
    __shared__ float Qs[64][64];
    __shared__ float Ks[64][64];
    int tid = threadIdx.x;
#pragma unroll
    for (int l = 0; l < 16; l++) {
        int e = tid + 256 * l;
        int dt = e >> 6, i = e & 63;
        int d = dt & 31;
        const float* sq = (dt < 32) ? q1 : q2;
        const float* sk = (dt < 32) ? k1 : k2;
        Qs[dt][i] = sq[((size_t)b * CC + h * 32 + d) * NQ + i];
        Ks[dt][i] = sk[((size_t)b * CC + h * 32 + d) * NQ + i];
    }
    __syncthreads();
    int i = tid & 63, jg = tid >> 6;
    float acc[16] = {};
    for (int dt = 0; dt < 64; dt++) {
        float qv = Qs[dt][i];
#pragma unroll
        for (int t = 0; t < 16; t++) acc[t] += qv * Ks[dt][jg * 16 + t];
    }
    float* outp = attn_s + (((size_t)(b * 8 + h) * 64 + i) * 64) + jg * 16;
#pragma unroll
    for (int t = 0; t < 16; t++) outp[t] = acc[t];
}

// ===========================================================================
// Split-K flash-style attention PV with MFMA. V from (B,N,C) bf16 via LDS
// transpose staging (coalesced 64B global reads).
// ===========================================================================
__global__ __launch_bounds__(256) void attn_pv_k(
    const float* __restrict__ attn_s, const unsigned short* __restrict__ v16,
    float* __restrict__ part_O, float* __restrict__ part_rs) {
    __shared__ float asub[64][68];
    __shared__ float Mq[64];
    __shared__ unsigned short Vs[32][72];
    __shared__ short po4[64][4];
    __shared__ float pw4[64][4];
    int s = blockIdx.x, bh = blockIdx.y;
    int b = bh >> 3, h = bh & 7;
    int tid = threadIdx.x;
    int lane = tid & 63, wv = tid >> 6;
    int quad = lane >> 4, l16 = lane & 15;
    {
        int q = tid & 63, jg = tid >> 6;
        const float* src = attn_s + ((size_t)bh * 64 + q) * 64 + jg * 16;
        float* dst = &asub[q][jg * 16];
#pragma unroll
        for (int t = 0; t < 4; t++) {
            floatx4 f = *(const floatx4*)(src + t * 4);
            f[0] *= SCALEF; f[1] *= SCALEF; f[2] *= SCALEF; f[3] *= SCALEF;
            *(floatx4*)(dst + t * 4) = f;
        }
    }
    __syncthreads();
    if (tid < 64) {
        float mx = asub[tid][0];
        for (int j = 1; j < 64; j++) mx = fmaxf(mx, asub[tid][j]);
        Mq[tid] = mx;
    }
    __syncthreads();
    int q = wv * 16 + l16;
    float Mv = Mq[q];
    floatx4 zero = {0.f, 0.f, 0.f, 0.f};
    floatx4 acc0 = zero, acc1 = zero;
    float rsum = 0.f;
    for (int cch = 0; cch < 7; cch++) {
        int n0 = (s * 7 + cch) * 64;
        {
            int n_loc = tid >> 2, doct = tid & 3;
            short8 vv = *(const short8*)(const short*)(v16 +
                ((size_t)(b * NN + n0 + n_loc)) * CC + h * 32 + doct * 8);
#pragma unroll
            for (int j = 0; j < 8; j++)
                Vs[doct * 8 + j][n_loc] = (unsigned short)vv[j];
        }
        if (tid < 64) {
            int n = n0 + tid;
            int oy = n / WWD, ox = n - oy * WWD;
            float sy = (oy + 0.5f) * 0.14285714285714285f - 0.5f;
            float sx = (ox + 0.5f) * 0.14285714285714285f - 0.5f;
            float fy0 = floorf(sy), fx0 = floorf(sx);
            int y0 = (int)fy0, x0 = (int)fx0;
            float fy = sy - fy0, fx = sx - fx0;
            int y0c = max(y0, 0), y1c = min(y0 + 1, 7);
            int x0c = max(x0, 0), x1c = min(x0 + 1, 7);
            po4[tid][0] = (short)(y0c * 8 + x0c);
            po4[tid][1] = (short)(y0c * 8 + x1c);
            po4[tid][2] = (short)(y1c * 8 + x0c);
            po4[tid][3] = (short)(y1c * 8 + x1c);
            pw4[tid][0] = (1.f - fy) * (1.f - fx);
            pw4[tid][1] = (1.f - fy) * fx;
            pw4[tid][2] = fy * (1.f - fx);
            pw4[tid][3] = fy * fx;
        }
        __syncthreads();
#pragma unroll
        for (int kc = 0; kc < 2; kc++) {
            short8 af;
#pragma unroll
            for (int j = 0; j < 8; j++) {
                int np = kc * 32 + quad * 8 + j;
                float val = pw4[np][0] * asub[q][po4[np][0]]
                          + pw4[np][1] * asub[q][po4[np][1]]
                          + pw4[np][2] * asub[q][po4[np][2]]
                          + pw4[np][3] * asub[q][po4[np][3]];
                float p = exp2f((val - Mv) * 1.44269504f);
                rsum += p;
                af[j] = (short)f2bf(p);
            }
            short8 bf0 = *(const short8*)&Vs[l16][kc * 32 + quad * 8];
            short8 bf1 = *(const short8*)&Vs[16 + l16][kc * 32 + quad * 8];
            acc0 = __builtin_amdgcn_mfma_f32_16x16x32_bf16(af, bf0, acc0, 0, 0, 0);
            acc1 = __builtin_amdgcn_mfma_f32_16x16x32_bf16(af, bf1, acc1, 0, 0, 0);
        }
        __syncthreads();
    }
    rsum += __shfl_xor(rsum, 16, 64);
    rsum += __shfl_xor(rsum, 32, 64);
    size_t base = ((size_t)bh * 7 + s) * 64;
    if (lane < 16) part_rs[base + wv * 16 + lane] = rsum;
#pragma unroll
    for (int nt = 0; nt < 2; nt++) {
        floatx4 a = nt ? acc1 : acc0;
#pragma unroll
        for (int r = 0; r < 4; r++) {
            int qo = wv * 16 + quad * 4 + r;
            part_O[(base + qo) * 32 + nt * 16 + l16] = a[r];
        }
    }
}

// reduce split-K partials -> out_small (B, 64q, C) fp32 (coalesced in d)
__global__ __launch_bounds__(256) void attn_red_k(
    const float* __restrict__ part_O, const float* __restrict__ part_rs,
    float* __restrict__ out_sm) {
    int idx = blockIdx.x * 256 + threadIdx.x;  // 64bh * 64q * 32d
    int d = idx & 31, q = (idx >> 5) & 63, bh = idx >> 11;
    float o = 0.f, rs = 0.f;
    for (int s = 0; s < 7; s++) {
        size_t base = ((size_t)bh * 7 + s) * 64;
        o += part_O[(base + q) * 32 + d];
        rs += part_rs[base + q];
    }
    int b = bh >> 3, h = bh & 7;
    out_sm[((size_t)b * 64 + q) * CC + h * 32 + d] = o / rs;
}

// bilinear upsample (B,64,C) fp32 -> (B,N,C) bf16, coalesced in c
__global__ __launch_bounds__(256) void upsample_nhwc_k(
    const float* __restrict__ osm, unsigned short* __restrict__ U16) {
    int blk = blockIdx.x;  // b*NN + n
    int b = blk / NN, n = blk % NN;
    int c = threadIdx.x;
    int y = n / WWD, x = n - y * WWD;
    float sy = (y + 0.5f) * 0.14285714285714285f - 0.5f;
    float sx = (x + 0.5f) * 0.14285714285714285f - 0.5f;
    float fy0 = floorf(sy), fx0 = floorf(sx);
    int y0 = (int)fy0, x0 = (int)fx0;
    float fy = sy - fy0, fx = sx - fx0;
    int y0c = max(y0, 0), y1c = min(y0 + 1, 7);
    int x0c = max(x0, 0), x1c = min(x0 + 1, 7);
    const float* basep = osm + (size_t)b * 64 * CC + c;
    float v00 = basep[(size_t)(y0c * 8 + x0c) * CC];
    float v01 = basep[(size_t)(y0c * 8 + x1c) * CC];
    float v10 = basep[(size_t)(y1c * 8 + x0c) * CC];
    float v11 = basep[(size_t)(y1c * 8 + x1c) * CC];
    float val = (1.f - fy) * ((1.f - fx) * v00 + fx * v01) +
                fy * ((1.f - fx) * v10 + fx * v11);
    U16[(size_t)blk * CC + c] = f2bf(val);
}

// ===========================================================================
// Final projection MFMA: y[m, co] = sum_{k<512} cat[m,k]*W[co,k] + bias[co]
// Both K-halves now (B,N,C) bf16 -> pure 16B staging copies.
// ===========================================================================
__global__ __launch_bounds__(256) void proj_mfma(
    const unsigned short* __restrict__ xh16, const unsigned short* __restrict__ xl16,
    const unsigned short* __restrict__ w16, const float* __restrict__ bias,
    float* __restrict__ y) {
    __shared__ short As[128 * 72];
    __shared__ short Bs[64 * 72];
    int m0 = blockIdx.x * 128, c0 = blockIdx.y * 64;
    int tid = threadIdx.x;
    int lane = tid & 63, wv = tid >> 6;
    int quad = lane >> 4, l16 = lane & 15;
    floatx4 zero = {0.f, 0.f, 0.f, 0.f};
    floatx4 acc[2][4];
#pragma unroll
    for (int mi = 0; mi < 2; mi++)
#pragma unroll
        for (int ci = 0; ci < 4; ci++) acc[mi][ci] = zero;

    for (int k0 = 0; k0 < 512; k0 += 64) {
        const unsigned short* srcb = (k0 < 256) ? xh16 : xl16;
        int kb = k0 & 255;
#pragma unroll
        for (int i2 = 0; i2 < 4; i2++) {
            int idx = tid + 256 * i2;
            int m = idx >> 3, o = idx & 7;
            *(short8*)&As[m * 72 + o * 8] =
                *(const short8*)(const short*)(srcb + (size_t)(m0 + m) * CC + kb + o * 8);
        }
#pragma unroll
        for (int i2 = 0; i2 < 2; i2++) {
            int idx = tid + 256 * i2;
            int c = idx >> 3, o = idx & 7;
            *(short8*)&Bs[c * 72 + o * 8] =
                *(const short8*)(const short*)(w16 + (size_t)(c0 + c) * DIMM + k0 + o * 8);
        }
        __syncthreads();
#pragma unroll
        for (int kc = 0; kc < 2; kc++) {
            short8 af[2], bf[4];
#pragma unroll
            for (int mi = 0; mi < 2; mi++)
                af[mi] = *(const short8*)&As[(wv * 32 + mi * 16 + l16) * 72 + (kc * 4 + quad) * 8];
#pragma unroll
            for (int ci = 0; ci < 4; ci++)
                bf[ci] = *(const short8*)&Bs[(ci * 16 + l16) * 72 + (kc * 4 + quad) * 8];
#pragma unroll
            for (int mi = 0; mi < 2; mi++)
#pragma unroll
                for (int ci = 0; ci < 4; ci++)
                    acc[mi][ci] = __builtin_amdgcn_mfma_f32_16x16x32_bf16(
                        af[mi], bf[ci], acc[mi][ci], 0, 0, 0);
        }
        __syncthreads();
    }
#pragma unroll
    for (int mi = 0; mi < 2; mi++) {
        int mbase = m0 + wv * 32 + mi * 16 + quad * 4;
#pragma unroll
        for (int ci = 0; ci < 4; ci++) {
            int co = c0 + ci * 16 + l16;
            float bi = bias[co];
#pragma unroll
            for (int r = 0; r < 4; r++)
                y[(size_t)(mbase + r) * DIMM + co] = acc[mi][ci][r] + bi;
        }
    }
}

extern "C" void kernel_launch(void* const* d_in, const int* in_sizes, int n_in,
                              void* d_out, int out_size, void* d_ws, size_t ws_size,
                              hipStream_t stream) {
    const float* x        = (const float*)d_in[0];
    const float* proj_v_w = (const float*)d_in[1];
    const float* conv1_w  = (const float*)d_in[2];
    const float* conv2_w  = (const float*)d_in[3];
    const float* conv3_w  = (const float*)d_in[4];
    const float* conv3_b  = (const float*)d_in[5];
    const float* v_conv_w = (const float*)d_in[6];
    const float* proj_w   = (const float*)d_in[7];
    const float* proj_b   = (const float*)d_in[8];
    const float* bn1_g = (const float*)d_in[9],  *bn1_b = (const float*)d_in[10];
    const float* bn1_m = (const float*)d_in[11], *bn1_v = (const float*)d_in[12];
    const float* bn2_g = (const float*)d_in[13], *bn2_b = (const float*)d_in[14];
    const float* bn2_m = (const float*)d_in[15], *bn2_v = (const float*)d_in[16];
    const float* bn3_g = (const float*)d_in[17], *bn3_b = (const float*)d_in[18];
    const float* bn3_m = (const float*)d_in[19], *bn3_v = (const float*)d_in[20];
    const float* vbn_g = (const float*)d_in[21], *vbn_b = (const float*)d_in[22];
    const float* vbn_m = (const float*)d_in[23], *vbn_v = (const float*)d_in[24];

    const size_t big = (size_t)BB * CC * NN;  // 6,422,528 elements
    unsigned short* v16    = (unsigned short*)d_ws;  // v (B,N,C)
    unsigned short* bn1_16 = v16 + big;              // bn1 (B,N,C) (pool input)
    unsigned short* g1_16  = bn1_16 + big;           // gelu(bn1) (B,N,C)
    unsigned short* bn2_16 = g1_16 + big;            // bn2 (B,N,C)
    unsigned short* xh16   = bn2_16 + big;           // x_high (B,N,C)
    unsigned short* U16    = xh16 + big;             // upsampled (B,N,C)
    unsigned short* xlow16 = U16 + big;              // x_low (B,N,C)
    float* small = (float*)(xlow16 + big);
    float* q1 = small;
    float* q2 = q1 + (size_t)BB * CC * NQ;
    float* k1 = q2 + (size_t)BB * CC * NQ;
    float* k2 = k1 + (size_t)BB * CC * NQ;
    float* attn_s = k2 + (size_t)BB * CC * NQ;               // (B,NH,64,64)
    float* out_sm = attn_s + (size_t)BB * NHEAD * NQ * NQ;   // (B,64,C)
    float* part_O = out_sm + (size_t)BB * NQ * CC;           // 64*7*64*32
    float* part_rs = part_O + (size_t)64 * 7 * 64 * 32;      // 64*7*64
    unsigned short* w16v  = (unsigned short*)(part_rs + 64 * 7 * 64);
    unsigned short* w16c3 = w16v + 65536;
    unsigned short* w16p  = w16c3 + 65536;  // 262144 shorts

    cast_k<<<256, 256, 0, stream>>>(proj_v_w, w16v, 65536);
    cast_k<<<256, 256, 0, stream>>>(conv3_w, w16c3, 65536);
    cast_k<<<1024, 256, 0, stream>>>(proj_w, w16p, 262144);

    gemm_v_mfma<<<dim3(196, 4), 256, 0, stream>>>(x, w16v, v16);
    dwconv_nhwc_k<true><<<BB * NN / 2, 256, 0, stream>>>(
        v16, conv1_w, bn1_g, bn1_b, bn1_m, bn1_v, bn1_16, g1_16);
    pool_nhwc_k<<<BB * 64, 256, 0, stream>>>(bn1_16, q1, q2);
    dwconv_nhwc_k<false><<<BB * NN / 2, 256, 0, stream>>>(
        g1_16, conv2_w, bn2_g, bn2_b, bn2_m, bn2_v, bn2_16, nullptr);
    pool_nhwc_k<<<BB * 64, 256, 0, stream>>>(bn2_16, k1, k2);
    conv3_mfma<<<dim3(196, 4), 256, 0, stream>>>(bn2_16, w16c3, conv3_b,
                                                 bn3_g, bn3_b, bn3_m, bn3_v, xh16);
    attn_qk_k<<<64, 256, 0, stream>>>(q1, q2, k1, k2, attn_s);
    attn_pv_k<<<dim3(7, 64), 256, 0, stream>>>(attn_s, v16, part_O, part_rs);
    attn_red_k<<<512, 256, 0, stream>>>(part_O, part_rs, out_sm);
    upsample_nhwc_k<<<BB * NN, 256, 0, stream>>>(out_sm, U16);
    dwconv_nhwc_k<false><<<BB * NN / 2, 256, 0, stream>>>(
        U16, v_conv_w, vbn_g, vbn_b, vbn_m, vbn_v, xlow16, nullptr);
    proj_mfma<<<dim3(196, 8), 256, 0, stream>>>(xh16, xlow16, w16p, proj_b, (float*)d_out);
}